// Round 1
// 417.589 us; speedup vs baseline: 1.2422x; 1.2422x over previous
//
#include <hip/hip_runtime.h>
#include <hip/hip_bf16.h>

// Spatial RNN, 4 directions, R=8, C=64.
// One block per (direction, line). Line = row (left/right) or column (up/down).
// Reversed directions (right/down) handled by negative pixel strides so the
// local recurrence is always t[p] = relu(t[p-1] @ W), t[-1] = 0.
//
// MFMA mapping (16x16x32 bf16): D[d][p] = sum_c W[c][d] * t[p-1][c]
//   A-operand = W^T fragments (regs), M = out-channel
//   B-operand = t fragments from LDS, N = pixel
// D-fragment: pixel = lane&15, channel = dt*16 + (lane>>4)*4 + reg.
//
// v2 (occupancy restructure):
//  - SINGLE in-place t buffer (27.8 KB, was 55.8 KB double buffer) ->
//    4-5 blocks/CU instead of 2. Per step: read ALL B fragments -> barrier ->
//    MFMA/relu/acc/pack -> in-place write -> barrier. Write targets slot p+1,
//    reads were from slots p; barriers make it race-free across waves.
//  - acc initialized from direct x fragment loads (folds "out = x + sum"),
//    output stored directly from acc fragments (4 lanes = 64B contiguous
//    chunks = full write sectors). Deletes the fp32 LDS staging (which was
//    the 8-way-bank-conflict hotspot) and the second x read.

#define HD 192
#define CH 64
#define RSTEPS 8
#define TSTRIDE 72   // shorts per pixel row (64 + 8 pad -> 144B = 36 banks)
#define SLOTS 193    // pixel slots incl. zero slot at index 0 (= t[-1])

typedef __attribute__((ext_vector_type(8))) short short8v;
typedef __attribute__((ext_vector_type(4))) float float4v;

static __device__ __forceinline__ short f2bf_rne(float f) {
    unsigned u = __float_as_uint(f);
    u += 0x7FFFu + ((u >> 16) & 1u);
    return (short)(u >> 16);
}

__global__ __launch_bounds__(256, 4) void spatial_rnn_kernel(
    const float* __restrict__ x,
    const float* __restrict__ Wl,
    const float* __restrict__ Wr,
    const float* __restrict__ Wu,
    const float* __restrict__ Wd,
    float* __restrict__ out)
{
    __shared__ __align__(16) short tb[SLOTS * TSTRIDE];   // 27,792 B

    const int tid  = threadIdx.x;
    const int dir  = blockIdx.y;
    const int line = blockIdx.x;
    const int b    = line / HD;
    const int rc   = line - b * HD;

    const float* Wp = (dir == 0) ? Wl : (dir == 1) ? Wr : (dir == 2) ? Wu : Wd;

    int xbase, xstride, obase, ostride;
    if (dir == 0) {        // left: out[w] uses in[w-1]; forward along w
        xbase   = (b * HD + rc) * HD * CH;
        xstride = CH;
        obase   = (b * HD + rc) * HD * 256;
        ostride = 256;
    } else if (dir == 1) { // right: out[w] uses in[w+1]; reversed along w
        xbase   = ((b * HD + rc) * HD + (HD - 1)) * CH;
        xstride = -CH;
        obase   = ((b * HD + rc) * HD + (HD - 1)) * 256 + 64;
        ostride = -256;
    } else if (dir == 2) { // up: out[h] uses in[h-1]; forward along h
        xbase   = b * HD * HD * CH + rc * CH;
        xstride = HD * CH;
        obase   = b * HD * HD * 256 + rc * 256 + 128;
        ostride = HD * 256;
    } else {               // down: out[h] uses in[h+1]; reversed along h
        xbase   = ((b * HD + (HD - 1)) * HD + rc) * CH;
        xstride = -HD * CH;
        obase   = ((b * HD + (HD - 1)) * HD + rc) * 256 + 192;
        ostride = -HD * 256;
    }

    const int lane = tid & 63;
    const int wv   = tid >> 6;
    const int q4   = lane >> 4;
    const int l16  = lane & 15;

    // zero slot 0 (= t[-1], never written again)
    if (tid < TSTRIDE) tb[tid] = 0;

    // ---- x fragment loads: acc init (folds the final "+x") + t0 -> LDS ----
    float4v acc[3][4];
    #pragma unroll
    for (int i = 0; i < 3; ++i) {
        const int p = (wv + i * 4) * 16 + l16;   // pixel owned by this lane
        #pragma unroll
        for (int dt = 0; dt < 4; ++dt) {
            const float4 v = *(const float4*)(x + xbase + p * xstride + dt * 16 + q4 * 4);
            acc[i][dt] = (float4v){v.x, v.y, v.z, v.w};
            __hip_bfloat162 h01 = __float22bfloat162_rn(make_float2(v.x, v.y));
            __hip_bfloat162 h23 = __float22bfloat162_rn(make_float2(v.z, v.w));
            uint2 wpk;
            __builtin_memcpy(&wpk.x, &h01, 4);
            __builtin_memcpy(&wpk.y, &h23, 4);
            // t0[pixel p][channels dt*16 + q4*4 .. +3] -> slot p+1
            *(uint2*)(tb + (p + 1) * TSTRIDE + dt * 16 + q4 * 4) = wpk;
        }
    }

    // ---- W fragments (A operand): A[d][c] = W[c][d] ----
    short8v Af[2][4];
    #pragma unroll
    for (int kc = 0; kc < 2; ++kc)
        #pragma unroll
        for (int dt = 0; dt < 4; ++dt)
            #pragma unroll
            for (int j = 0; j < 8; ++j)
                Af[kc][dt][j] = f2bf_rne(Wp[(kc * 32 + q4 * 8 + j) * CH + dt * 16 + l16]);

    __syncthreads();

    // ---- 8 recurrent steps, single buffer, in place ----
    // read ALL B fragments -> barrier -> compute + in-place write -> barrier
    for (int k = 0; k < RSTEPS; ++k) {
        short8v B0[3], B1[3];
        #pragma unroll
        for (int i = 0; i < 3; ++i) {
            const int slot = (wv + i * 4) * 16 + l16;  // slot p holds t_prev[p-1]
            B0[i] = *(const short8v*)(tb + slot * TSTRIDE + q4 * 8);
            B1[i] = *(const short8v*)(tb + slot * TSTRIDE + 32 + q4 * 8);
        }
        __syncthreads();   // all reads done before anyone writes
        #pragma unroll
        for (int i = 0; i < 3; ++i) {
            const int pb = (wv + i * 4) * 16;
            #pragma unroll
            for (int dt = 0; dt < 4; ++dt) {
                float4v d = {0.f, 0.f, 0.f, 0.f};
                d = __builtin_amdgcn_mfma_f32_16x16x32_bf16(Af[0][dt], B0[i], d, 0, 0, 0);
                d = __builtin_amdgcn_mfma_f32_16x16x32_bf16(Af[1][dt], B1[i], d, 0, 0, 0);
                float v0 = fmaxf(d[0], 0.f);
                float v1 = fmaxf(d[1], 0.f);
                float v2 = fmaxf(d[2], 0.f);
                float v3 = fmaxf(d[3], 0.f);
                acc[i][dt][0] += v0; acc[i][dt][1] += v1;
                acc[i][dt][2] += v2; acc[i][dt][3] += v3;
                if (k < RSTEPS - 1) {
                    __hip_bfloat162 h01 = __float22bfloat162_rn(make_float2(v0, v1));
                    __hip_bfloat162 h23 = __float22bfloat162_rn(make_float2(v2, v3));
                    uint2 wpk;
                    __builtin_memcpy(&wpk.x, &h01, 4);
                    __builtin_memcpy(&wpk.y, &h23, 4);
                    // t_new[pixel pb+l16][channel dt*16 + q4*4 + r] -> slot p+1
                    *(uint2*)(tb + (pb + l16 + 1) * TSTRIDE + dt * 16 + q4 * 4) = wpk;
                }
            }
        }
        if (k < RSTEPS - 1) __syncthreads();   // writes visible before next reads
    }

    // ---- store: out = acc (x folded in at init) ----
    // lanes q4=0..3 of one pixel cover 64B contiguous -> full write sectors
    #pragma unroll
    for (int i = 0; i < 3; ++i) {
        const int p = (wv + i * 4) * 16 + l16;
        #pragma unroll
        for (int dt = 0; dt < 4; ++dt) {
            float4 o;
            o.x = acc[i][dt][0]; o.y = acc[i][dt][1];
            o.z = acc[i][dt][2]; o.w = acc[i][dt][3];
            *(float4*)(out + obase + p * ostride + dt * 16 + q4 * 4) = o;
        }
    }
}

extern "C" void kernel_launch(void* const* d_in, const int* in_sizes, int n_in,
                              void* d_out, int out_size, void* d_ws, size_t ws_size,
                              hipStream_t stream) {
    const float* x  = (const float*)d_in[0];
    const float* Wl = (const float*)d_in[1];
    const float* Wr = (const float*)d_in[2];
    const float* Wu = (const float*)d_in[3];
    const float* Wd = (const float*)d_in[4];
    float* outp = (float*)d_out;
    dim3 grid(8 * HD, 4);
    spatial_rnn_kernel<<<grid, 256, 0, stream>>>(x, Wl, Wr, Wu, Wd, outp);
}